// Round 2
// baseline (98.835 us; speedup 1.0000x reference)
//
#include <hip/hip_runtime.h>

// MorphologicalLayer: ops='co', windows=[51,25] on [16, 8, 262144] f32.
// Reference chains 4 stages, EACH with fresh zero 'same' padding:
//   y1 = max51(zpad(x)); y2 = min51(zpad(y1)); y3 = min25(zpad(y2)); out = max25(zpad(y3))
// Fused single kernel: stage tiles through LDS, per-thread register doubling.
// Per-stage zero padding is reproduced by zeroing stage outputs whose global
// index falls outside [0, L) (edge tiles only).

#define L_ROW   262144
#define N_ROWS  128          // B*C = 16*8
#define T_VALID 3996         // valid outputs per tile (4-aligned)
#define N_TILES 66           // ceil(262144 / 3996)
#define BLOCK   256
#define E       16           // outputs per thread per stage
#define IN_SLOTS 1040        // float4 slots staged from global (4160 floats)
#define BUF_SLOTS 1088       // buffer size in float4 slots (mult. of 8 for swizzle)

// XOR swizzle at float4 granularity: spreads per-thread 128B-strided chunks
// across all 8 bank-quads (32 banks / 4 per float4). Bijective on [0,1088).
__device__ __forceinline__ int swz(int s) { return s ^ ((s >> 3) & 7); }

template<int N, int D, bool MX>
__device__ __forceinline__ void pass(float* r) {
#pragma unroll
  for (int i = 0; i < N; ++i)
    r[i] = MX ? fmaxf(r[i], r[i + D]) : fminf(r[i], r[i + D]);
}

// One morphology stage: reads E + K - 1 floats per thread from src (LDS),
// window-K min/max via log-doubling fully in registers, writes E floats to dst.
// goff = global index (in the intermediate signal) of dst local coord 0.
// edge: zero outputs mapping outside [0, L) — the reference's per-stage padding.
template<int K, bool MX>
__device__ __forceinline__ void stage(const float4* __restrict__ src,
                                      float4* __restrict__ dst, int tid,
                                      int goff, bool edge) {
  constexpr int NIN = E + K - 1;        // 66 (K=51) or 40 (K=25)
  constexpr int NF4 = (NIN + 3) / 4;    // 17 or 10
  float r[NF4 * 4];
  const int b4 = tid * (E / 4);
#pragma unroll
  for (int j = 0; j < NF4; ++j) {
    float4 v = src[swz(b4 + j)];
    r[4*j+0] = v.x; r[4*j+1] = v.y; r[4*j+2] = v.z; r[4*j+3] = v.w;
  }
  if constexpr (K == 51) {
    // window doubling: 1,2,4,8,16,32 then combine w32[i], w32[i+19] -> w51
    pass<65, 1, MX>(r);
    pass<63, 2, MX>(r);
    pass<59, 4, MX>(r);
    pass<51, 8, MX>(r);
    pass<35,16, MX>(r);
    pass<16,19, MX>(r);
  } else { // K == 25: 1,2,4,8,16 then w16[i], w16[i+9] -> w25
    pass<39, 1, MX>(r);
    pass<37, 2, MX>(r);
    pass<33, 4, MX>(r);
    pass<25, 8, MX>(r);
    pass<16, 9, MX>(r);
  }
  if (edge) {
    const int base = goff + tid * E;
#pragma unroll
    for (int i = 0; i < E; ++i)
      if ((unsigned)(base + i) >= (unsigned)L_ROW) r[i] = 0.0f;
  }
#pragma unroll
  for (int j = 0; j < E / 4; ++j)
    dst[swz(b4 + j)] = make_float4(r[4*j], r[4*j+1], r[4*j+2], r[4*j+3]);
}

__global__ __launch_bounds__(BLOCK)
void morph_co_kernel(const float* __restrict__ x, float* __restrict__ out) {
  __shared__ float4 bufA[BUF_SLOTS];
  __shared__ float4 bufB[BUF_SLOTS];

  const int tid  = threadIdx.x;
  const int tile = blockIdx.x;
  const int row  = blockIdx.y;
  const float* __restrict__ xrow = x   + (size_t)row * L_ROW;
  float* __restrict__       orow = out + (size_t)row * L_ROW;

  // c0 = global input index of local coord 0.  -76 keeps c0 4-aligned
  // (>= 74 halo); final outputs live at local coords [2, 3998).
  const int c0 = tile * T_VALID - 76;
  const bool edge = (tile == 0) || (tile == N_TILES - 1);

  // ---- stage 0: global -> LDS (zero-fill outside the row = input zero pad)
  for (int s = tid; s < IN_SLOTS; s += BLOCK) {
    const int g = c0 + 4 * s;
    float4 v;
    if (g >= 0 && g + 3 < L_ROW) {
      v = *reinterpret_cast<const float4*>(xrow + g);   // c0 is 4-aligned
    } else {
      v.x = ((unsigned)(g + 0) < (unsigned)L_ROW) ? xrow[g + 0] : 0.0f;
      v.y = ((unsigned)(g + 1) < (unsigned)L_ROW) ? xrow[g + 1] : 0.0f;
      v.z = ((unsigned)(g + 2) < (unsigned)L_ROW) ? xrow[g + 2] : 0.0f;
      v.w = ((unsigned)(g + 3) < (unsigned)L_ROW) ? xrow[g + 3] : 0.0f;
    }
    bufA[swz(s)] = v;
  }
  __syncthreads();

  // ---- closing (k=51): dilation, erosion; opening (k=25): erosion, dilation
  // dst local l maps to intermediate-signal global index c0 + l + OFS,
  // OFS = 25, 50, 62, 74 respectively.
  stage<51, true >(bufA, bufB, tid, c0 + 25, edge); __syncthreads();
  stage<51, false>(bufB, bufA, tid, c0 + 50, edge); __syncthreads();
  stage<25, false>(bufA, bufB, tid, c0 + 62, edge); __syncthreads();
  stage<25, true >(bufB, bufA, tid, c0 + 74, edge); __syncthreads();

  // ---- copy-out: local coord i+2 -> out[ob + i], coalesced scalar stores
  const float* bf = reinterpret_cast<const float*>(bufA);
  const int ob = tile * T_VALID;
  const int n  = min(T_VALID, L_ROW - ob);
  for (int i = tid; i < n; i += BLOCK) {
    const int f  = i + 2;
    const int sl = swz(f >> 2);
    orow[ob + i] = bf[sl * 4 + (f & 3)];
  }
}

extern "C" void kernel_launch(void* const* d_in, const int* in_sizes, int n_in,
                              void* d_out, int out_size, void* d_ws, size_t ws_size,
                              hipStream_t stream) {
  const float* x = (const float*)d_in[0];
  float* out = (float*)d_out;
  dim3 grid(N_TILES, N_ROWS);
  morph_co_kernel<<<grid, BLOCK, 0, stream>>>(x, out);
}

// Round 3
// 70.119 us; speedup vs baseline: 1.4095x; 1.4095x over previous
//
#include <hip/hip_runtime.h>

// MorphologicalLayer: ops='co', windows=[51,25] on [16, 8, 262144] f32.
// Reference chains 4 stages, EACH with fresh zero 'same' padding:
//   y1 = max51(zp(x)); y2 = min51(zp(y1)); y3 = min25(zp(y2)); y4 = max25(zp(y3))
// Interior (>=37 from row ends): min25∘min51 == min75, so interior tiles run
// 3 fused stages; the two edge tiles run the exact 4-stage chain with
// per-stage zero clamps. Single in-place LDS buffer, per-thread register
// log-doubling, E=32 outputs/thread.

#define L_ROW   262144
#define N_ROWS  128          // B*C = 16*8
#define BLOCK   256
#define E       32           // outputs per thread per stage
#define EF4     8            // E/4
#define T_VALID 8040         // valid outputs per tile (4-aligned, <= 8192-150)
#define N_TILES 33           // ceil(262144 / 8040)
#define STAGE_F4 2048        // float4 slots staged from global (8192 floats)
#define BUF_SLOTS 2072       // buffer float4 slots (max read slot 2066; mult of 8)

// XOR swizzle at float4 granularity: spreads per-thread 128B-strided chunks
// across all 8 bank-quads. Involution, bijective on any mult-of-8 range.
__device__ __forceinline__ int swz(int s) { return s ^ ((s >> 3) & 7); }

template<int N, int D, bool MX>
__device__ __forceinline__ void pass(float* r) {
#pragma unroll
  for (int i = 0; i < N; ++i)
    r[i] = MX ? fmaxf(r[i], r[i + D]) : fminf(r[i], r[i + D]);
}

// In-place stage: read E+K-1 floats from buf into regs, barrier, window-K
// min/max via log-doubling, optional per-stage zero clamp (edge tiles),
// write E floats back, barrier.  Final r[i] depends only on src [i, i+K-1],
// so garbage beyond the valid region never contaminates valid outputs.
template<int K, bool MX>
__device__ __forceinline__ void stage_ip(float4* buf, int tid, int goff, bool edge) {
  constexpr int NIN = E + K - 1;        // 82 / 106 / 56
  constexpr int NF4 = (NIN + 3) / 4;    // 21 / 27 / 14
  float r[NF4 * 4];
  const int b4 = tid * EF4;
#pragma unroll
  for (int j = 0; j < NF4; ++j) {
    float4 v = buf[swz(b4 + j)];
    r[4*j+0] = v.x; r[4*j+1] = v.y; r[4*j+2] = v.z; r[4*j+3] = v.w;
  }
  __syncthreads();   // all reads complete before any in-place write
  if constexpr (K == 51) {
    pass<81, 1, MX>(r); pass<79, 2, MX>(r); pass<75, 4, MX>(r);
    pass<67, 8, MX>(r); pass<51,16, MX>(r); pass<32,19, MX>(r);
  } else if constexpr (K == 75) {
    pass<105, 1, MX>(r); pass<103, 2, MX>(r); pass<99, 4, MX>(r);
    pass< 91, 8, MX>(r); pass< 75,16, MX>(r); pass<43,32, MX>(r);
    pass< 32,11, MX>(r);
  } else { // K == 25
    pass<55, 1, MX>(r); pass<53, 2, MX>(r); pass<49, 4, MX>(r);
    pass<41, 8, MX>(r); pass<32, 9, MX>(r);
  }
  if (edge) {
    const int base = goff + tid * E;
#pragma unroll
    for (int i = 0; i < E; ++i)
      if ((unsigned)(base + i) >= (unsigned)L_ROW) r[i] = 0.0f;
  }
#pragma unroll
  for (int j = 0; j < EF4; ++j)
    buf[swz(b4 + j)] = make_float4(r[4*j], r[4*j+1], r[4*j+2], r[4*j+3]);
  __syncthreads();
}

__global__ __launch_bounds__(BLOCK)
void morph_co_kernel(const float* __restrict__ x, float* __restrict__ out) {
  __shared__ float4 buf[BUF_SLOTS];

  const int tid  = threadIdx.x;
  const int tile = blockIdx.x;
  const int row  = blockIdx.y;
  const float* __restrict__ xrow = x   + (size_t)row * L_ROW;
  float* __restrict__       orow = out + (size_t)row * L_ROW;

  // c0 = global input index of buffer float 0; 4-aligned; halo 76 left.
  // Final outputs land at buffer floats [2, T_VALID+2).
  const int c0 = tile * T_VALID - 76;
  const bool edge = (tile == 0) || (tile == N_TILES - 1);

  // ---- staging: global -> LDS
  if (!edge) {
#pragma unroll
    for (int k = 0; k < STAGE_F4 / BLOCK; ++k) {
      const int s = k * BLOCK + tid;
      buf[swz(s)] = *reinterpret_cast<const float4*>(xrow + c0 + 4 * s);
    }
  } else {
#pragma unroll
    for (int k = 0; k < STAGE_F4 / BLOCK; ++k) {
      const int s = k * BLOCK + tid;
      const int g = c0 + 4 * s;
      float4 v;
      if (g >= 0 && g + 3 < L_ROW) {
        v = *reinterpret_cast<const float4*>(xrow + g);
      } else {
        v.x = ((unsigned)(g + 0) < (unsigned)L_ROW) ? xrow[g + 0] : 0.0f;
        v.y = ((unsigned)(g + 1) < (unsigned)L_ROW) ? xrow[g + 1] : 0.0f;
        v.z = ((unsigned)(g + 2) < (unsigned)L_ROW) ? xrow[g + 2] : 0.0f;
        v.w = ((unsigned)(g + 3) < (unsigned)L_ROW) ? xrow[g + 3] : 0.0f;
      }
      buf[swz(s)] = v;
    }
  }
  __syncthreads();

  if (!edge) {
    // interior: max51 -> min75 (fused min51∘min25) -> max25, no pads touch
    stage_ip<51, true >(buf, tid, 0, false);
    stage_ip<75, false>(buf, tid, 0, false);
    stage_ip<25, true >(buf, tid, 0, false);
  } else {
    // exact chain with per-stage zero padding (offsets 25/50/62/74)
    stage_ip<51, true >(buf, tid, c0 + 25, true);
    stage_ip<51, false>(buf, tid, c0 + 50, true);
    stage_ip<25, false>(buf, tid, c0 + 62, true);
    stage_ip<25, true >(buf, tid, c0 + 74, true);
  }

  // ---- copy-out: buffer float i+2 -> out[ob + i], coalesced scalar stores
  const float* bf = reinterpret_cast<const float*>(buf);
  const int ob = tile * T_VALID;
  const int n  = min(T_VALID, L_ROW - ob);
  for (int i = tid; i < n; i += BLOCK) {
    const int f  = i + 2;
    const int sl = swz(f >> 2);
    orow[ob + i] = bf[sl * 4 + (f & 3)];
  }
}

extern "C" void kernel_launch(void* const* d_in, const int* in_sizes, int n_in,
                              void* d_out, int out_size, void* d_ws, size_t ws_size,
                              hipStream_t stream) {
  const float* x = (const float*)d_in[0];
  float* out = (float*)d_out;
  dim3 grid(N_TILES, N_ROWS);
  morph_co_kernel<<<grid, BLOCK, 0, stream>>>(x, out);
}

// Round 4
// 58.816 us; speedup vs baseline: 1.6804x; 1.1922x over previous
//
#include <hip/hip_runtime.h>

// MorphologicalLayer: ops='co', windows=[51,25] on [16, 8, 262144] f32.
// Reference chains 4 stages, EACH with fresh zero 'same' padding:
//   y1 = max51(zp(x)); y2 = min51(zp(y1)); y3 = min25(zp(y2)); y4 = max25(zp(y3))
// Interior tiles fuse min51∘min25 = min75 (3 stages); the two edge tiles run
// the exact 4-stage chain with per-stage zero clamps.
// Stage algorithm: van Herk/Gil-Werman suffix/prefix scans in registers
// (3-4 ops/elem instead of log-doubling's 12-17). Own 32-elem block stays in
// registers across stages; only the halo is re-read from LDS each stage.

#define L_ROW   262144
#define N_ROWS  128          // B*C = 16*8
#define BLOCK   256
#define E       32           // elements per thread
#define EF4     8            // E/4
#define T_VALID 8040         // valid outputs per tile (4-aligned)
#define N_TILES 33           // ceil(262144 / 8040)
#define BUF_SLOTS 2072       // tile buffer float4 slots (max slot read: 2066)

// XOR swizzle at float4 granularity: spreads per-thread 128B-strided accesses
// across all 8 bank-quads. Involution, bijective on mult-of-8 ranges.
__device__ __forceinline__ int swz(int s) { return s ^ ((s >> 3) & 7); }

template<bool MX>
__device__ __forceinline__ float mm(float a, float b) {
  return MX ? fmaxf(a, b) : fminf(a, b);
}

// One in-place stage. On entry r[0..31] = own block of current-stage input.
// Reads halo floats [32 .. K+30] from LDS, computes left-aligned window-K
// min/max via suffix/prefix scans, leaves outputs in r[0..31].
// edge: zero outputs mapping outside [0,L) (the reference's per-stage pad).
// WB: write outputs back to LDS (with the two barriers the in-place buffer
// needs); final stage uses WB=true too so copy-out can read neighbors.
template<int K, bool MX, bool WB>
__device__ __forceinline__ void stage_scan(float* r, float4* buf, int tid,
                                           int goff, bool edge) {
  static_assert(K == 25 || K >= 33, "two-boundary path is K=25-specific");
  constexpr int JMAX = K + 30;            // highest float index used
  constexpr int HF4  = (JMAX >> 2) - 7;   // halo f4 slots: [8 .. JMAX>>2]
  const int b4 = tid * EF4;
#pragma unroll
  for (int j = 0; j < HF4; ++j) {
    float4 v = buf[swz(b4 + 8 + j)];
    r[32 + 4*j] = v.x; r[33 + 4*j] = v.y; r[34 + 4*j] = v.z; r[35 + 4*j] = v.w;
  }
  if constexpr (WB) __syncthreads();  // all halo reads done before overwrite

  if constexpr (K >= 33) {
    // every window [i, i+K-1], i in [0,32), straddles the boundary at 32
#pragma unroll
    for (int i = 30; i >= 0; --i) r[i] = mm<MX>(r[i], r[i + 1]);       // S
#pragma unroll
    for (int j = 33; j <= JMAX; ++j) r[j] = mm<MX>(r[j - 1], r[j]);    // P
#pragma unroll
    for (int i = 0; i < E; ++i) r[i] = mm<MX>(r[i], r[i + K - 1]);     // out
  } else {
    // K=25: chunk A (i in [0,16)) straddles 16; chunk B (i in [16,32)) straddles 32
    float tp[16];
    float c = r[16];
#pragma unroll
    for (int j = 17; j <= 39; ++j) {              // P_A = mm(x[16..j]), j in [24,39]
      c = mm<MX>(c, r[j]);
      if (j >= 24) tp[j - 24] = c;
    }
#pragma unroll
    for (int i = 14; i >= 0; --i) r[i] = mm<MX>(r[i], r[i + 1]);       // S_A
#pragma unroll
    for (int i = 0; i < 16; ++i) r[i] = mm<MX>(r[i], tp[i]);           // out A
#pragma unroll
    for (int i = 30; i >= 16; --i) r[i] = mm<MX>(r[i], r[i + 1]);      // S_B
#pragma unroll
    for (int j = 33; j <= 55; ++j) r[j] = mm<MX>(r[j - 1], r[j]);      // P_B
#pragma unroll
    for (int i = 16; i < 32; ++i) r[i] = mm<MX>(r[i], r[i + 24]);      // out B
  }

  if (edge) {
    const int base = goff + tid * E;
#pragma unroll
    for (int i = 0; i < E; ++i)
      if ((unsigned)(base + i) >= (unsigned)L_ROW) r[i] = 0.0f;
  }
  if constexpr (WB) {
#pragma unroll
    for (int j = 0; j < EF4; ++j)
      buf[swz(b4 + j)] = make_float4(r[4*j], r[4*j+1], r[4*j+2], r[4*j+3]);
    __syncthreads();
  }
}

__global__ __launch_bounds__(BLOCK)
void morph_co_kernel(const float* __restrict__ x, float* __restrict__ out) {
  __shared__ float4 buf[BUF_SLOTS];

  const int tid  = threadIdx.x;
  const int tile = blockIdx.x;
  const int row  = blockIdx.y;
  const float* __restrict__ xrow = x   + (size_t)row * L_ROW;
  float* __restrict__       orow = out + (size_t)row * L_ROW;

  // c0 = global input index of buffer float 0; 4-aligned; halo 76 left.
  // Final outputs land at buffer floats [2, T_VALID+2).
  const int c0 = tile * T_VALID - 76;
  const bool edge = (tile == 0) || (tile == N_TILES - 1);

  // ---- staging: global -> LDS (zero-fill outside the row = input zero pad)
  if (!edge) {
    for (int s = tid; s < BUF_SLOTS; s += BLOCK)
      buf[swz(s)] = *reinterpret_cast<const float4*>(xrow + c0 + 4 * s);
  } else {
    for (int s = tid; s < BUF_SLOTS; s += BLOCK) {
      const int g = c0 + 4 * s;
      float4 v;
      if (g >= 0 && g + 3 < L_ROW) {
        v = *reinterpret_cast<const float4*>(xrow + g);
      } else {
        v.x = ((unsigned)(g + 0) < (unsigned)L_ROW) ? xrow[g + 0] : 0.0f;
        v.y = ((unsigned)(g + 1) < (unsigned)L_ROW) ? xrow[g + 1] : 0.0f;
        v.z = ((unsigned)(g + 2) < (unsigned)L_ROW) ? xrow[g + 2] : 0.0f;
        v.w = ((unsigned)(g + 3) < (unsigned)L_ROW) ? xrow[g + 3] : 0.0f;
      }
      buf[swz(s)] = v;
    }
  }
  __syncthreads();

  // own block -> registers (persists across stages)
  float r[108];
  {
    const int b4 = tid * EF4;
#pragma unroll
    for (int j = 0; j < EF4; ++j) {
      float4 v = buf[swz(b4 + j)];
      r[4*j] = v.x; r[4*j+1] = v.y; r[4*j+2] = v.z; r[4*j+3] = v.w;
    }
  }

  if (!edge) {
    // interior: max51 -> min75 (= min25∘min51) -> max25; pads never reached
    stage_scan<51, true,  true>(r, buf, tid, 0, false);
    stage_scan<75, false, true>(r, buf, tid, 0, false);
    stage_scan<25, true,  true>(r, buf, tid, 0, false);
  } else {
    // exact chain with per-stage zero padding (offsets 25/50/62/74)
    stage_scan<51, true,  true>(r, buf, tid, c0 + 25, true);
    stage_scan<51, false, true>(r, buf, tid, c0 + 50, true);
    stage_scan<25, false, true>(r, buf, tid, c0 + 62, true);
    stage_scan<25, true,  true>(r, buf, tid, c0 + 74, true);
  }

  // ---- copy-out: buffer float i+2 -> out[ob + i], coalesced scalar stores
  const float* bf = reinterpret_cast<const float*>(buf);
  const int ob = tile * T_VALID;
  const int n  = min(T_VALID, L_ROW - ob);
  for (int i = tid; i < n; i += BLOCK) {
    const int f = i + 2;
    orow[ob + i] = bf[swz(f >> 2) * 4 + (f & 3)];
  }
}

extern "C" void kernel_launch(void* const* d_in, const int* in_sizes, int n_in,
                              void* d_out, int out_size, void* d_ws, size_t ws_size,
                              hipStream_t stream) {
  const float* x = (const float*)d_in[0];
  float* out = (float*)d_out;
  dim3 grid(N_TILES, N_ROWS);
  morph_co_kernel<<<grid, BLOCK, 0, stream>>>(x, out);
}

// Round 5
// 51.878 us; speedup vs baseline: 1.9051x; 1.1337x over previous
//
#include <hip/hip_runtime.h>

// MorphologicalLayer: ops='co', windows=[51,25] on [16, 8, 262144] f32.
//   y1 = max51(zp(x)); y2 = min51(zp(y1)); y3 = min25(zp(y2)); y4 = max25(zp(y3))
// Interior tiles fuse min51∘min25 = min75 (3 stages); the two edge tiles run
// the exact 4-stage chain with per-stage zero clamps.
// Two-level (blocked-8 + aggregate cascade) suffix/prefix scans: dep chains
// ~10 ops instead of 50-105. Own 32-elem block lives in registers across
// stages; halo re-read from LDS. 32 KiB LDS -> 5 blocks/CU.

#define L_ROW   262144
#define N_ROWS  128          // B*C = 16*8
#define BLOCK   256
#define E       32           // elements per thread
#define EF4     8            // E/4
#define T_VALID 7996         // valid outputs per tile (4-aligned)
#define N_TILES 33           // ceil(262144 / 7996)
#define BUF_SLOTS 2048       // 32 KiB exactly -> 5 blocks/CU LDS-wise

// XOR swizzle at float4 granularity: spreads per-thread 128B-strided accesses
// across all 8 bank-quads. Involution, bijective on mult-of-8 ranges.
__device__ __forceinline__ int swz(int s) { return s ^ ((s >> 3) & 7); }

template<bool MX>
__device__ __forceinline__ float mm(float a, float b) {
  return MX ? fmaxf(a, b) : fminf(a, b);
}

__device__ __forceinline__ void edge_zero(float* r, int goff, int tid, bool edge) {
  if (edge) {
    const int base = goff + tid * E;
#pragma unroll
    for (int i = 0; i < E; ++i)
      if ((unsigned)(base + i) >= (unsigned)L_ROW) r[i] = 0.0f;
  }
}

__device__ __forceinline__ void writeback(const float* r, float4* buf, int b4) {
#pragma unroll
  for (int j = 0; j < EF4; ++j)
    buf[swz(b4 + j)] = make_float4(r[4*j], r[4*j+1], r[4*j+2], r[4*j+3]);
  __syncthreads();
}

// K in {51, 75}: all windows [i, i+K-1], i in [0,32), straddle the boundary
// at 32. out[i] = mm(S[i], Base&Top prefix at i+K-1).
template<int K, bool MX>
__device__ __forceinline__ void stage_big(float* r, float4* buf, int tid,
                                          int goff, bool edge) {
  constexpr int BLEN = K - 33;              // 18 / 42 (== 2 mod 4)
  constexpr int BN   = (BLEN + 2) / 4;      // 5 / 11 base-side f4 slots
  const int b4 = tid * EF4;
  const int bh = min(b4, 2032 - BN);        // max slot bh+15+BN <= 2047

  // Base = mm over halo floats [32 .. K-2], lane-wise accumulators (low regs)
  float4 v0 = buf[swz(bh + 8)];
  float a0 = v0.x, a1 = v0.y, a2 = v0.z, a3 = v0.w;
#pragma unroll
  for (int j = 1; j < BN - 1; ++j) {
    float4 v = buf[swz(bh + 8 + j)];
    a0 = mm<MX>(a0, v.x); a1 = mm<MX>(a1, v.y);
    a2 = mm<MX>(a2, v.z); a3 = mm<MX>(a3, v.w);
  }
  float4 vl = buf[swz(bh + 8 + BN - 1)];    // 2 base floats + T[0], T[1]
  const float Base = mm<MX>(mm<MX>(mm<MX>(a0, a1), mm<MX>(a2, a3)),
                            mm<MX>(vl.x, vl.y));
  // Top: halo floats [K-1 .. K+30]
  float T[34];
  T[0] = vl.z; T[1] = vl.w;
#pragma unroll
  for (int j = 0; j < 8; ++j) {
    float4 v = buf[swz(bh + 8 + BN + j)];
    T[2+4*j] = v.x; T[3+4*j] = v.y; T[4+4*j] = v.z; T[5+4*j] = v.w;
  }
  __syncthreads();   // all halo reads complete before any in-place write

  // S[i] = mm(r[i..31]) via blocked-8 suffix + cascade (in place)
#pragma unroll
  for (int b = 0; b < 4; ++b)
#pragma unroll
    for (int i = 8*b + 6; i >= 8*b; --i) r[i] = mm<MX>(r[i], r[i+1]);
  const float S2 = r[24];
  const float S1 = mm<MX>(r[16], S2);
  const float S0 = mm<MX>(r[8],  S1);
#pragma unroll
  for (int i = 0;  i < 8;  ++i) r[i] = mm<MX>(r[i], S0);
#pragma unroll
  for (int i = 8;  i < 16; ++i) r[i] = mm<MX>(r[i], S1);
#pragma unroll
  for (int i = 16; i < 24; ++i) r[i] = mm<MX>(r[i], S2);

  // Top prefix within blocks of 8 + head cascade
#pragma unroll
  for (int b = 0; b < 4; ++b)
#pragma unroll
    for (int i = 8*b + 1; i < 8*b + 8; ++i) T[i] = mm<MX>(T[i-1], T[i]);
  const float G0 = mm<MX>(Base, T[7]);
  const float G1 = mm<MX>(G0,   T[15]);
  const float G2 = mm<MX>(G1,   T[23]);

  // out[i] = mm(S[i], head, T[i])  (nested fmax/fmin can fuse to v_max3/min3)
#pragma unroll
  for (int i = 0;  i < 8;  ++i) r[i] = mm<MX>(r[i], mm<MX>(Base, T[i]));
#pragma unroll
  for (int i = 8;  i < 16; ++i) r[i] = mm<MX>(r[i], mm<MX>(G0, T[i]));
#pragma unroll
  for (int i = 16; i < 24; ++i) r[i] = mm<MX>(r[i], mm<MX>(G1, T[i]));
#pragma unroll
  for (int i = 24; i < 32; ++i) r[i] = mm<MX>(r[i], mm<MX>(G2, T[i]));

  edge_zero(r, goff, tid, edge);
  writeback(r, buf, b4);
}

// K = 25: chunk A (i in [0,16)) straddles 16; chunk B (i in [16,32)) straddles 32.
template<bool MX>
__device__ __forceinline__ void stage_25(float* r, float4* buf, int tid,
                                         int goff, bool edge) {
  const int b4 = tid * EF4;
  const int bh = min(b4, 2034);             // max slot bh+13 <= 2047
  float h[24];                              // halo floats [32..55]
#pragma unroll
  for (int j = 0; j < 6; ++j) {
    float4 v = buf[swz(bh + 8 + j)];
    h[4*j] = v.x; h[4*j+1] = v.y; h[4*j+2] = v.z; h[4*j+3] = v.w;
  }
  __syncthreads();

  // t = prefix over raw r[24..31] (before in-place S destroys it)
  float t[8];
  t[0] = r[24];
#pragma unroll
  for (int i = 1; i < 8; ++i) t[i] = mm<MX>(t[i-1], r[24+i]);
  // S_B over r[16..31] (blocked)
#pragma unroll
  for (int i = 30; i >= 24; --i) r[i] = mm<MX>(r[i], r[i+1]);
#pragma unroll
  for (int i = 22; i >= 16; --i) r[i] = mm<MX>(r[i], r[i+1]);
  const float cA = r[16];                   // mm(raw r[16..23])
  const float A3 = r[24];
#pragma unroll
  for (int i = 16; i < 24; ++i) r[i] = mm<MX>(r[i], A3);
  // S_A over r[0..15]
#pragma unroll
  for (int i = 14; i >= 8; --i) r[i] = mm<MX>(r[i], r[i+1]);
#pragma unroll
  for (int i = 6;  i >= 0; --i) r[i] = mm<MX>(r[i], r[i+1]);
  const float A1 = r[8];
#pragma unroll
  for (int i = 0; i < 8; ++i) r[i] = mm<MX>(r[i], A1);
  // halo prefix in blocks of 8
#pragma unroll
  for (int b = 0; b < 3; ++b)
#pragma unroll
    for (int i = 8*b + 1; i < 8*b + 8; ++i) h[i] = mm<MX>(h[i-1], h[i]);
  const float aB  = h[7];                   // mm(abs 32..39)
  const float cA2 = mm<MX>(cA, t[7]);       // mm(abs 16..31)
  const float G1  = mm<MX>(aB, h[15]);      // mm(abs 32..47)
  // out[i] = mm(S, head, scan)   windows [i, i+24]
#pragma unroll
  for (int i = 0;  i < 8;  ++i) r[i] = mm<MX>(r[i], mm<MX>(cA,  t[i]));
#pragma unroll
  for (int i = 8;  i < 16; ++i) r[i] = mm<MX>(r[i], mm<MX>(cA2, h[i-8]));
#pragma unroll
  for (int i = 16; i < 24; ++i) r[i] = mm<MX>(r[i], mm<MX>(aB,  h[i-8]));
#pragma unroll
  for (int i = 24; i < 32; ++i) r[i] = mm<MX>(r[i], mm<MX>(G1,  h[i-8]));

  edge_zero(r, goff, tid, edge);
  writeback(r, buf, b4);
}

__global__ __launch_bounds__(BLOCK)
void morph_co_kernel(const float* __restrict__ x, float* __restrict__ out) {
  __shared__ float4 buf[BUF_SLOTS];

  const int tid  = threadIdx.x;
  const int tile = blockIdx.x;
  const int row  = blockIdx.y;
  const float* __restrict__ xrow = x   + (size_t)row * L_ROW;
  float* __restrict__       orow = out + (size_t)row * L_ROW;

  // c0 = global input index of buffer float 0; 4-aligned; halo 76 left.
  // Final outputs land at buffer floats [2, T_VALID+2).
  const int c0 = tile * T_VALID - 76;
  const bool edge = (tile == 0) || (tile == N_TILES - 1);

  // ---- staging: global -> LDS (swizzled layout)
  if (!edge) {
#if __has_builtin(__builtin_amdgcn_global_load_lds)
    // linear LDS dest + inverse-swizzled global source == swizzled layout
    const int w = tid >> 6, lane = tid & 63;
#pragma unroll
    for (int k = 0; k < 8; ++k) {
      const int q0 = k * 256 + w * 64;
      const float* g = xrow + c0 + 4 * swz(q0 + lane);
      __builtin_amdgcn_global_load_lds(
          (const __attribute__((address_space(1))) void*)g,
          (__attribute__((address_space(3))) void*)(&buf[q0]), 16, 0, 0);
    }
#else
#pragma unroll
    for (int k = 0; k < 8; ++k) {
      const int s = k * BLOCK + tid;
      buf[swz(s)] = *reinterpret_cast<const float4*>(xrow + c0 + 4 * s);
    }
#endif
  } else {
#pragma unroll
    for (int k = 0; k < 8; ++k) {
      const int s = k * BLOCK + tid;
      const int g = c0 + 4 * s;
      float4 v;
      if (g >= 0 && g + 3 < L_ROW) {
        v = *reinterpret_cast<const float4*>(xrow + g);
      } else {
        v.x = ((unsigned)(g + 0) < (unsigned)L_ROW) ? xrow[g + 0] : 0.0f;
        v.y = ((unsigned)(g + 1) < (unsigned)L_ROW) ? xrow[g + 1] : 0.0f;
        v.z = ((unsigned)(g + 2) < (unsigned)L_ROW) ? xrow[g + 2] : 0.0f;
        v.w = ((unsigned)(g + 3) < (unsigned)L_ROW) ? xrow[g + 3] : 0.0f;
      }
      buf[swz(s)] = v;
    }
  }
  __syncthreads();

  // own block -> registers (persists across stages)
  float r[E];
  {
    const int b4 = tid * EF4;
#pragma unroll
    for (int j = 0; j < EF4; ++j) {
      float4 v = buf[swz(b4 + j)];
      r[4*j] = v.x; r[4*j+1] = v.y; r[4*j+2] = v.z; r[4*j+3] = v.w;
    }
  }

  if (!edge) {
    // interior: max51 -> min75 (= min25∘min51) -> max25; pads never reached
    stage_big<51, true >(r, buf, tid, 0, false);
    stage_big<75, false>(r, buf, tid, 0, false);
    stage_25 <     true>(r, buf, tid, 0, false);
  } else {
    // exact chain with per-stage zero padding (offsets 25/50/62/74)
    stage_big<51, true >(r, buf, tid, c0 + 25, true);
    stage_big<51, false>(r, buf, tid, c0 + 50, true);
    stage_25 <    false>(r, buf, tid, c0 + 62, true);
    stage_25 <     true>(r, buf, tid, c0 + 74, true);
  }

  // ---- copy-out: buffer floats [2, n+2) -> out[ob .. ob+n), float4 stores
  const int ob  = tile * T_VALID;
  const int nf4 = min(T_VALID, L_ROW - ob) >> 2;
  float4* og = reinterpret_cast<float4*>(orow + ob);   // 16B aligned
  for (int u = tid; u < nf4; u += BLOCK) {
    float4 a = buf[swz(u)];
    float4 b = buf[swz(u + 1)];
    og[u] = make_float4(a.z, a.w, b.x, b.y);
  }
}

extern "C" void kernel_launch(void* const* d_in, const int* in_sizes, int n_in,
                              void* d_out, int out_size, void* d_ws, size_t ws_size,
                              hipStream_t stream) {
  const float* x = (const float*)d_in[0];
  float* out = (float*)d_out;
  dim3 grid(N_TILES, N_ROWS);
  morph_co_kernel<<<grid, BLOCK, 0, stream>>>(x, out);
}